// Round 10
// baseline (245.073 us; speedup 1.0000x reference)
//
#include <hip/hip_runtime.h>

#define F_IN 64
#define F_OUT 40
#define USTRIDE 20       // uint32 per bf16 row (40 bf16 = 80 B)
#define QPN 5            // uint4 (8 bf16) chunks per row; 5 lanes per node

#define PART_BLK 256
#define PART_EPB 16
#define PART_TILE (PART_BLK * PART_EPB)     // 4096 edges per partition block
#define BSHIFT 8                            // 256 nodes per bucket
#define BCAP 4096                           // staging slots per bucket (mean 3277, +14 sigma)
#define MAXB 512                            // >= nbk=391 (and scan width)

#define WSTRIDE 17                          // W LDS row stride in float4 (bank-conflict-free)

// ---- bf16 helpers (round-to-nearest-even, pack 2 per uint) ----
__device__ inline unsigned pk2(float x, float y) {
    unsigned a = __float_as_uint(x); a = (a + 0x7FFFu + ((a >> 16) & 1u)) >> 16;
    unsigned b = __float_as_uint(y); b = (b + 0x7FFFu + ((b >> 16) & 1u)) >> 16;
    return a | (b << 16);
}
__device__ inline void up2(unsigned u, float& a, float& b) {
    a = __uint_as_float(u << 16); b = __uint_as_float(u & 0xFFFF0000u);
}

// ---------------- phase A: multisplit partition into dst-buckets ----------------
// bucket b staging region: [b*BCAP, ...). record: src(17b) | dstLow(8b)<<17.
// bfill[b] holds pure COUNTS (memset 0 before launch); per-edge atomics are
// LDS-only; one global atomic per (block,bucket).
__global__ __launch_bounds__(PART_BLK) void partition_kernel(const int* __restrict__ src,
                                                             const int* __restrict__ dst,
                                                             int* __restrict__ bfill,
                                                             unsigned* __restrict__ staging,
                                                             int E, int nbk) {
    __shared__ int hist[MAXB];
    __shared__ int base[MAXB];
    int tid = threadIdx.x;
    for (int b = tid; b < nbk; b += PART_BLK) hist[b] = 0;
    __syncthreads();

    int rank[PART_EPB];
    int bk[PART_EPB];
    unsigned rec[PART_EPB];
    int eb = blockIdx.x * PART_TILE + tid;
#pragma unroll
    for (int k = 0; k < PART_EPB; ++k) {
        int e = eb + k * PART_BLK;
        if (e < E) {
            int r = src[e];
            int c = dst[e];
            int b = c >> BSHIFT;
            bk[k] = b;
            rec[k] = (unsigned)r | ((unsigned)(c & 255) << 17);
            rank[k] = atomicAdd(&hist[b], 1);
        } else {
            bk[k] = -1;
        }
    }
    __syncthreads();
    for (int b = tid; b < nbk; b += PART_BLK) {
        int h = hist[b];
        base[b] = h ? (b * BCAP + atomicAdd(&bfill[b], h)) : 0;
    }
    __syncthreads();
#pragma unroll
    for (int k = 0; k < PART_EPB; ++k) {
        if (bk[k] >= 0) staging[base[bk[k]] + rank[k]] = rec[k];
    }
}

// ---------------- bucket-total scan (one block): ebase = exclusive prefix ----------------
__global__ __launch_bounds__(512) void btotal_scan_kernel(const int* __restrict__ bfill,
                                                          int* __restrict__ ebase,
                                                          int* __restrict__ rowptr_end,
                                                          int nbk, int E) {
    __shared__ int s[512];
    int tid = threadIdx.x;
    int v = (tid < nbk) ? bfill[tid] : 0;
    s[tid] = v;
    __syncthreads();
    for (int off = 1; off < 512; off <<= 1) {
        int t = (tid >= off) ? s[tid - off] : 0;
        __syncthreads();
        s[tid] += t;
        __syncthreads();
    }
    if (tid < nbk) ebase[tid] = s[tid] - v;
    if (tid == 0) *rowptr_end = E;
}

// ---------------- per-bucket finalize: hist -> scan -> rowptr/deg/dinv + scatter ------
// Also emits a within-bucket degree-DESCENDING node permutation (bitonic sort of
// 256 keys in LDS) so propagate waves see uniform loop trip counts.
__global__ __launch_bounds__(256) void bucket_finalize_kernel(const unsigned* __restrict__ staging,
                                                              const int* __restrict__ bfill,
                                                              const int* __restrict__ ebase,
                                                              int* __restrict__ rowptr,
                                                              int* __restrict__ deg,
                                                              float* __restrict__ dinv,
                                                              float* __restrict__ dinv2,
                                                              int* __restrict__ srcs,
                                                              int* __restrict__ perm, int n) {
    int b = blockIdx.x;
    __shared__ int h[256];
    __shared__ int cur[256];
    __shared__ unsigned keys[256];
    int tid = threadIdx.x;
    h[tid] = 0;
    __syncthreads();

    int cnt = bfill[b];
    const unsigned* rec = staging + (size_t)b * BCAP;
    for (int i = tid; i < cnt; i += 256) {
        atomicAdd(&h[rec[i] >> 17], 1);
    }
    __syncthreads();

    int v = h[tid];
    // sort key: deg desc, then local id asc (so valid nodes precede pad nodes on ties)
    keys[tid] = ((unsigned)v << 8) | (unsigned)(255 - tid);

    // inclusive Hillis-Steele scan of h
    for (int off = 1; off < 256; off <<= 1) {
        int t = (tid >= off) ? h[tid - off] : 0;
        __syncthreads();
        h[tid] += t;
        __syncthreads();
    }
    int excl = h[tid] - v;
    int base = ebase[b];
    int node = (b << BSHIFT) | tid;
    if (node < n) {
        rowptr[node] = base + excl;
        deg[node] = v;
        float r = rsqrtf((float)v + 1.0f);
        dinv[node] = r;
        dinv2[node] = r * r;
    }
    cur[tid] = base + excl;
    __syncthreads();

    // CSR scatter (LDS cursors; writes confined to this bucket's contiguous region)
    for (int i = tid; i < cnt; i += 256) {
        unsigned rv = rec[i];
        int pos = atomicAdd(&cur[rv >> 17], 1);
        srcs[pos] = (int)(rv & 0x1FFFFu);
    }
    __syncthreads();

    // bitonic sort keys DESCENDING (256 elems, 256 threads)
    for (int k = 2; k <= 256; k <<= 1) {
        for (int j = k >> 1; j > 0; j >>= 1) {
            int p = tid ^ j;
            if (p > tid) {
                unsigned a = keys[tid];
                unsigned c = keys[p];
                bool asc_region = ((tid & k) == 0);
                // descending overall: swap if out of order for DESC in asc_region
                if (asc_region ? (a < c) : (a > c)) {
                    keys[tid] = c;
                    keys[p] = a;
                }
            }
            __syncthreads();
        }
    }
    perm[(b << BSHIFT) | tid] = (b << BSHIFT) | (int)(255u - (keys[tid] & 255u));
}

// ---------------- projection u0 = dinv * (x @ W^T), bf16 out ----------------
// 2 nodes per thread (NB=2), 10 channels (q = t&3): halves W LDS wave-reads
// (proj was LDS-pipe-bound: 1M ds_read_b128 ~ 19us; now 500k).
__global__ __launch_bounds__(256, 4) void proj_kernel(const float* __restrict__ x,
                                                      const float* __restrict__ W,
                                                      const float* __restrict__ dinv,
                                                      unsigned* __restrict__ u, int n) {
    __shared__ float Ws[F_OUT * WSTRIDE * 4];
    for (int i = threadIdx.x; i < F_OUT * F_IN; i += 256) {
        int c = i >> 6;
        int k = i & 63;
        Ws[c * (WSTRIDE * 4) + k] = W[i];
    }
    __syncthreads();

    int t = blockIdx.x * 256 + threadIdx.x;
    int g = t >> 2;              // node-pair index
    int q = t & 3;
    int n0 = 2 * g;
    if (n0 >= n) return;
    int n1 = n0 + 1;             // N is even -> always valid

    const float4* xp0 = (const float4*)(x + (size_t)n0 * F_IN);
    const float4* xp1 = (const float4*)(x + (size_t)n1 * F_IN);
    const float4* Wq  = (const float4*)Ws + (size_t)(q * 10) * WSTRIDE;

    float acc0[10], acc1[10];
#pragma unroll
    for (int c = 0; c < 10; ++c) { acc0[c] = 0.0f; acc1[c] = 0.0f; }

#pragma unroll 1
    for (int f4 = 0; f4 < F_IN / 4; ++f4) {
        float4 x0 = xp0[f4];
        float4 x1 = xp1[f4];
#pragma unroll
        for (int c = 0; c < 10; ++c) {
            float4 w = Wq[c * WSTRIDE + f4];
            acc0[c] += x0.x * w.x + x0.y * w.y + x0.z * w.z + x0.w * w.w;
            acc1[c] += x1.x * w.x + x1.y * w.y + x1.z * w.z + x1.w * w.w;
        }
    }

    float d0 = dinv[n0];
    float d1 = dinv[n1];
    unsigned* up0 = u + (size_t)n0 * USTRIDE + q * 5;
    unsigned* up1 = u + (size_t)n1 * USTRIDE + q * 5;
#pragma unroll
    for (int j = 0; j < 5; ++j) {
        up0[j] = pk2(d0 * acc0[2 * j], d0 * acc0[2 * j + 1]);
        up1[j] = pk2(d1 * acc1[2 * j], d1 * acc1[2 * j + 1]);
    }
}

// ---------------- pull propagation (bf16 rows, fp32 accum) ----------------
// thread t: g = t/5 -> node = perm[g] (degree-sorted within bucket), q = t%5
// handles one uint4 (8 bf16, 16 B) of the 80 B row.
__global__ __launch_bounds__(256) void propagate_kernel(const int* __restrict__ perm,
                                                        const int* __restrict__ rowptr,
                                                        const int* __restrict__ srcs,
                                                        const float* __restrict__ dinv2,
                                                        const unsigned* __restrict__ ucur,
                                                        unsigned* __restrict__ unew, int n) {
    int t = blockIdx.x * blockDim.x + threadIdx.x;
    int g = t / QPN;
    int q = t - g * QPN;
    if (g >= n) return;
    int node = perm[g];

    int beg = rowptr[node];
    int end = rowptr[node + 1];

    const uint4* U = (const uint4*)ucur;    // row = 5 uint4
    uint4 sv = U[(size_t)node * QPN + q];   // self loop
    float a0, a1, a2, a3, a4, a5, a6, a7;
    up2(sv.x, a0, a1); up2(sv.y, a2, a3); up2(sv.z, a4, a5); up2(sv.w, a6, a7);

    int i = beg;
    for (; i + 3 < end; i += 4) {
        int s0 = srcs[i], s1 = srcs[i + 1], s2 = srcs[i + 2], s3 = srcs[i + 3];
        uint4 v0 = U[(size_t)s0 * QPN + q];
        uint4 v1 = U[(size_t)s1 * QPN + q];
        uint4 v2 = U[(size_t)s2 * QPN + q];
        uint4 v3 = U[(size_t)s3 * QPN + q];
        float b0, b1;
        up2(v0.x, b0, b1); a0 += b0; a1 += b1;
        up2(v0.y, b0, b1); a2 += b0; a3 += b1;
        up2(v0.z, b0, b1); a4 += b0; a5 += b1;
        up2(v0.w, b0, b1); a6 += b0; a7 += b1;
        up2(v1.x, b0, b1); a0 += b0; a1 += b1;
        up2(v1.y, b0, b1); a2 += b0; a3 += b1;
        up2(v1.z, b0, b1); a4 += b0; a5 += b1;
        up2(v1.w, b0, b1); a6 += b0; a7 += b1;
        up2(v2.x, b0, b1); a0 += b0; a1 += b1;
        up2(v2.y, b0, b1); a2 += b0; a3 += b1;
        up2(v2.z, b0, b1); a4 += b0; a5 += b1;
        up2(v2.w, b0, b1); a6 += b0; a7 += b1;
        up2(v3.x, b0, b1); a0 += b0; a1 += b1;
        up2(v3.y, b0, b1); a2 += b0; a3 += b1;
        up2(v3.z, b0, b1); a4 += b0; a5 += b1;
        up2(v3.w, b0, b1); a6 += b0; a7 += b1;
    }
    for (; i < end; ++i) {
        uint4 v = U[(size_t)srcs[i] * QPN + q];
        float b0, b1;
        up2(v.x, b0, b1); a0 += b0; a1 += b1;
        up2(v.y, b0, b1); a2 += b0; a3 += b1;
        up2(v.z, b0, b1); a4 += b0; a5 += b1;
        up2(v.w, b0, b1); a6 += b0; a7 += b1;
    }

    float ds = dinv2[node];
    uint4 o;
    o.x = pk2(ds * a0, ds * a1);
    o.y = pk2(ds * a2, ds * a3);
    o.z = pk2(ds * a4, ds * a5);
    o.w = pk2(ds * a6, ds * a7);
    ((uint4*)unew)[(size_t)node * QPN + q] = o;
}

// ---------------- y = D^{1/2} u3 + bias, log_softmax -> fp32 d_out ----------------
__global__ void logsoftmax_kernel(const unsigned* __restrict__ u, float* __restrict__ out,
                                  const float* __restrict__ bias,
                                  const int* __restrict__ deg, int n) {
    int node = blockIdx.x * blockDim.x + threadIdx.x;
    if (node >= n) return;
    float sq = sqrtf((float)deg[node] + 1.0f);
    const uint4* up = (const uint4*)(u + (size_t)node * USTRIDE);
    float v[F_OUT];
#pragma unroll
    for (int g = 0; g < 5; ++g) {
        uint4 t = up[g];
        float a, b2;
        up2(t.x, a, b2); v[8 * g + 0] = sq * a + bias[8 * g + 0];
                         v[8 * g + 1] = sq * b2 + bias[8 * g + 1];
        up2(t.y, a, b2); v[8 * g + 2] = sq * a + bias[8 * g + 2];
                         v[8 * g + 3] = sq * b2 + bias[8 * g + 3];
        up2(t.z, a, b2); v[8 * g + 4] = sq * a + bias[8 * g + 4];
                         v[8 * g + 5] = sq * b2 + bias[8 * g + 5];
        up2(t.w, a, b2); v[8 * g + 6] = sq * a + bias[8 * g + 6];
                         v[8 * g + 7] = sq * b2 + bias[8 * g + 7];
    }
    float mx = -1e30f;
#pragma unroll
    for (int c = 0; c < F_OUT; ++c) mx = fmaxf(mx, v[c]);
    float se = 0.0f;
#pragma unroll
    for (int c = 0; c < F_OUT; ++c) se += __expf(v[c] - mx);
    float lse = mx + __logf(se);
    float4* p = (float4*)(out + (size_t)node * F_OUT);
#pragma unroll
    for (int c4 = 0; c4 < F_OUT / 4; ++c4) {
        float4 t;
        t.x = v[4 * c4 + 0] - lse; t.y = v[4 * c4 + 1] - lse;
        t.z = v[4 * c4 + 2] - lse; t.w = v[4 * c4 + 3] - lse;
        p[c4] = t;
    }
}

extern "C" void kernel_launch(void* const* d_in, const int* in_sizes, int n_in,
                              void* d_out, int out_size, void* d_ws, size_t ws_size,
                              hipStream_t stream) {
    const float* x  = (const float*)d_in[0];
    const int*   ei = (const int*)d_in[1];
    const float* W  = (const float*)d_in[2];
    const float* b  = (const float*)d_in[3];

    const int N = in_sizes[0] / F_IN;        // 100000
    const int E = in_sizes[1] / 2;           // 1280000
    const int* src = ei;
    const int* dst = ei + E;
    const int nbk = (N + (1 << BSHIFT) - 1) >> BSHIFT;   // 391

    // ---- workspace layout ----
    char* base = (char*)d_ws;
    size_t off = 0;
    auto alloc = [&](size_t bytes) {
        char* p = base + off;
        off = (off + bytes + 255) & ~(size_t)255;
        return p;
    };
    int*      deg_i   = (int*)     alloc((size_t)N * 4);
    float*    dinv    = (float*)   alloc((size_t)N * 4);
    float*    dinv2   = (float*)   alloc((size_t)N * 4);
    int*      rowptr  = (int*)     alloc((size_t)(N + 1) * 4);
    int*      bfill   = (int*)     alloc((size_t)MAXB * 4);
    int*      ebase   = (int*)     alloc((size_t)MAXB * 4);
    int*      perm    = (int*)     alloc((size_t)(nbk << BSHIFT) * 4);   // 100096 ints
    unsigned* staging = (unsigned*)alloc((size_t)nbk * BCAP * 4);        // 6.4 MB
    int*      srcs_s  = (int*)     alloc((size_t)E * 4);
    unsigned* uA      = (unsigned*)alloc((size_t)N * USTRIDE * 4);       // 8 MB
    unsigned* uB      = (unsigned*)alloc((size_t)N * USTRIDE * 4);       // 8 MB
    float*    outp    = (float*)d_out;

    // 1) partition edges into dst-buckets (bfill = counts, memset-initialized)
    hipMemsetAsync(bfill, 0, (size_t)nbk * 4, stream);
    partition_kernel<<<(E + PART_TILE - 1) / PART_TILE, PART_BLK, 0, stream>>>(
        src, dst, bfill, staging, E, nbk);

    // 2) bucket-total scan + per-bucket finalize (rowptr/deg/dinv + CSR + perm)
    btotal_scan_kernel<<<1, 512, 0, stream>>>(bfill, ebase, rowptr + N, nbk, E);
    bucket_finalize_kernel<<<nbk, 256, 0, stream>>>(staging, bfill, ebase, rowptr,
                                                    deg_i, dinv, dinv2, srcs_s, perm, N);

    // 3) projection u0 = dinv * (x @ W^T) -> bf16 uA  (2 nodes/thread, 4 lanes/pair)
    proj_kernel<<<((size_t)N * 2 + 255) / 256, 256, 0, stream>>>(x, W, dinv, uA, N);

    // 4) three pull hops in bf16 u-space: uA -> uB -> uA -> uB
    const int pt = N * QPN;                  // 500k threads
    const int pg = (pt + 255) / 256;
    propagate_kernel<<<pg, 256, 0, stream>>>(perm, rowptr, srcs_s, dinv2, uA, uB, N);
    propagate_kernel<<<pg, 256, 0, stream>>>(perm, rowptr, srcs_s, dinv2, uB, uA, N);
    propagate_kernel<<<pg, 256, 0, stream>>>(perm, rowptr, srcs_s, dinv2, uA, uB, N);

    // 5) y3 = D^{1/2} u3 + bias, log_softmax -> d_out (fp32)
    logsoftmax_kernel<<<(N + 255) / 256, 256, 0, stream>>>(uB, outp, b, deg_i, N);
}

// Round 11
// 211.954 us; speedup vs baseline: 1.1563x; 1.1563x over previous
//
#include <hip/hip_runtime.h>

#define F_IN 64
#define F_OUT 40
#define USTRIDE 20       // uint32 per bf16 row (40 bf16 = 80 B)
#define QPN 5            // uint4 (8 bf16) chunks per row; 5 lanes per node

#define PART_BLK 256
#define PART_EPB 16
#define PART_TILE (PART_BLK * PART_EPB)     // 4096 edges per partition block
#define BSHIFT 8                            // 256 nodes per bucket
#define BCAP 4096                           // staging slots per bucket (mean 3277, +14 sigma)
#define MAXB 512                            // >= nbk=391 (and scan width)

#define WSTRIDE 17                          // W LDS row stride in float4 (bank-conflict-free)
#define NPB 51                              // nodes per block in fused hop3 (51*5=255 threads)

// ---- bf16 helpers (round-to-nearest-even, pack 2 per uint) ----
__device__ inline unsigned pk2(float x, float y) {
    unsigned a = __float_as_uint(x); a = (a + 0x7FFFu + ((a >> 16) & 1u)) >> 16;
    unsigned b = __float_as_uint(y); b = (b + 0x7FFFu + ((b >> 16) & 1u)) >> 16;
    return a | (b << 16);
}
__device__ inline void up2(unsigned u, float& a, float& b) {
    a = __uint_as_float(u << 16); b = __uint_as_float(u & 0xFFFF0000u);
}

// ---------------- phase A: multisplit partition into dst-buckets ----------------
// bucket b staging region: [b*BCAP, ...). record: src(17b) | dstLow(8b)<<17.
// bfill[b] holds pure COUNTS (memset 0 before launch); per-edge atomics are
// LDS-only; one global atomic per (block,bucket).
__global__ __launch_bounds__(PART_BLK) void partition_kernel(const int* __restrict__ src,
                                                             const int* __restrict__ dst,
                                                             int* __restrict__ bfill,
                                                             unsigned* __restrict__ staging,
                                                             int E, int nbk) {
    __shared__ int hist[MAXB];
    __shared__ int base[MAXB];
    int tid = threadIdx.x;
    for (int b = tid; b < nbk; b += PART_BLK) hist[b] = 0;
    __syncthreads();

    int rank[PART_EPB];
    int bk[PART_EPB];
    unsigned rec[PART_EPB];
    int eb = blockIdx.x * PART_TILE + tid;
#pragma unroll
    for (int k = 0; k < PART_EPB; ++k) {
        int e = eb + k * PART_BLK;
        if (e < E) {
            int r = src[e];
            int c = dst[e];
            int b = c >> BSHIFT;
            bk[k] = b;
            rec[k] = (unsigned)r | ((unsigned)(c & 255) << 17);
            rank[k] = atomicAdd(&hist[b], 1);
        } else {
            bk[k] = -1;
        }
    }
    __syncthreads();
    for (int b = tid; b < nbk; b += PART_BLK) {
        int h = hist[b];
        base[b] = h ? (b * BCAP + atomicAdd(&bfill[b], h)) : 0;
    }
    __syncthreads();
#pragma unroll
    for (int k = 0; k < PART_EPB; ++k) {
        if (bk[k] >= 0) staging[base[bk[k]] + rank[k]] = rec[k];
    }
}

// ---------------- bucket-total scan (one block): ebase = exclusive prefix ----------------
__global__ __launch_bounds__(512) void btotal_scan_kernel(const int* __restrict__ bfill,
                                                          int* __restrict__ ebase,
                                                          int* __restrict__ rowptr_end,
                                                          int nbk, int E) {
    __shared__ int s[512];
    int tid = threadIdx.x;
    int v = (tid < nbk) ? bfill[tid] : 0;
    s[tid] = v;
    __syncthreads();
    for (int off = 1; off < 512; off <<= 1) {
        int t = (tid >= off) ? s[tid - off] : 0;
        __syncthreads();
        s[tid] += t;
        __syncthreads();
    }
    if (tid < nbk) ebase[tid] = s[tid] - v;
    if (tid == 0) *rowptr_end = E;
}

// ---------------- per-bucket finalize: hist -> scan -> rowptr/dinv + CSR scatter ------
__global__ __launch_bounds__(256) void bucket_finalize_kernel(const unsigned* __restrict__ staging,
                                                              const int* __restrict__ bfill,
                                                              const int* __restrict__ ebase,
                                                              int* __restrict__ rowptr,
                                                              float* __restrict__ dinv,
                                                              float* __restrict__ dinv2,
                                                              int* __restrict__ srcs, int n) {
    int b = blockIdx.x;
    __shared__ int h[256];
    __shared__ int cur[256];
    int tid = threadIdx.x;
    h[tid] = 0;
    __syncthreads();

    int cnt = bfill[b];
    const unsigned* rec = staging + (size_t)b * BCAP;
    for (int i = tid; i < cnt; i += 256) {
        atomicAdd(&h[rec[i] >> 17], 1);
    }
    __syncthreads();

    int v = h[tid];
    // inclusive Hillis-Steele scan of h
    for (int off = 1; off < 256; off <<= 1) {
        int t = (tid >= off) ? h[tid - off] : 0;
        __syncthreads();
        h[tid] += t;
        __syncthreads();
    }
    int excl = h[tid] - v;
    int base = ebase[b];
    int node = (b << BSHIFT) | tid;
    if (node < n) {
        rowptr[node] = base + excl;
        float r = rsqrtf((float)v + 1.0f);
        dinv[node] = r;
        dinv2[node] = r * r;
    }
    cur[tid] = base + excl;
    __syncthreads();

    // CSR scatter (LDS cursors; writes confined to this bucket's contiguous region)
    for (int i = tid; i < cnt; i += 256) {
        unsigned rv = rec[i];
        int pos = atomicAdd(&cur[rv >> 17], 1);
        srcs[pos] = (int)(rv & 0x1FFFFu);
    }
}

// ---------------- projection u0 = dinv * (x @ W^T), bf16 out ----------------
// 2 nodes per thread (NB=2), 10 channels (q = t&3): halves W LDS wave-reads.
__global__ __launch_bounds__(256, 4) void proj_kernel(const float* __restrict__ x,
                                                      const float* __restrict__ W,
                                                      const float* __restrict__ dinv,
                                                      unsigned* __restrict__ u, int n) {
    __shared__ float Ws[F_OUT * WSTRIDE * 4];
    for (int i = threadIdx.x; i < F_OUT * F_IN; i += 256) {
        int c = i >> 6;
        int k = i & 63;
        Ws[c * (WSTRIDE * 4) + k] = W[i];
    }
    __syncthreads();

    int t = blockIdx.x * 256 + threadIdx.x;
    int g = t >> 2;              // node-pair index
    int q = t & 3;
    int n0 = 2 * g;
    if (n0 >= n) return;
    int n1 = n0 + 1;             // N is even -> always valid

    const float4* xp0 = (const float4*)(x + (size_t)n0 * F_IN);
    const float4* xp1 = (const float4*)(x + (size_t)n1 * F_IN);
    const float4* Wq  = (const float4*)Ws + (size_t)(q * 10) * WSTRIDE;

    float acc0[10], acc1[10];
#pragma unroll
    for (int c = 0; c < 10; ++c) { acc0[c] = 0.0f; acc1[c] = 0.0f; }

#pragma unroll 1
    for (int f4 = 0; f4 < F_IN / 4; ++f4) {
        float4 x0 = xp0[f4];
        float4 x1 = xp1[f4];
#pragma unroll
        for (int c = 0; c < 10; ++c) {
            float4 w = Wq[c * WSTRIDE + f4];
            acc0[c] += x0.x * w.x + x0.y * w.y + x0.z * w.z + x0.w * w.w;
            acc1[c] += x1.x * w.x + x1.y * w.y + x1.z * w.z + x1.w * w.w;
        }
    }

    float d0 = dinv[n0];
    float d1 = dinv[n1];
    unsigned* up0 = u + (size_t)n0 * USTRIDE + q * 5;
    unsigned* up1 = u + (size_t)n1 * USTRIDE + q * 5;
#pragma unroll
    for (int j = 0; j < 5; ++j) {
        up0[j] = pk2(d0 * acc0[2 * j], d0 * acc0[2 * j + 1]);
        up1[j] = pk2(d1 * acc1[2 * j], d1 * acc1[2 * j + 1]);
    }
}

// ---------------- pull propagation (bf16 rows, fp32 accum), natural node order -------
// thread t: node = t/5, q = t%5 handles one uint4 (8 bf16, 16 B) of the 80 B row.
__global__ __launch_bounds__(256) void propagate_kernel(const int* __restrict__ rowptr,
                                                        const int* __restrict__ srcs,
                                                        const float* __restrict__ dinv2,
                                                        const unsigned* __restrict__ ucur,
                                                        unsigned* __restrict__ unew, int n) {
    int t = blockIdx.x * blockDim.x + threadIdx.x;
    int node = t / QPN;
    int q = t - node * QPN;
    if (node >= n) return;

    int beg = rowptr[node];
    int end = rowptr[node + 1];

    const uint4* U = (const uint4*)ucur;    // row = 5 uint4
    uint4 sv = U[(size_t)node * QPN + q];   // self loop
    float a0, a1, a2, a3, a4, a5, a6, a7;
    up2(sv.x, a0, a1); up2(sv.y, a2, a3); up2(sv.z, a4, a5); up2(sv.w, a6, a7);

    int i = beg;
    for (; i + 3 < end; i += 4) {
        int s0 = srcs[i], s1 = srcs[i + 1], s2 = srcs[i + 2], s3 = srcs[i + 3];
        uint4 v0 = U[(size_t)s0 * QPN + q];
        uint4 v1 = U[(size_t)s1 * QPN + q];
        uint4 v2 = U[(size_t)s2 * QPN + q];
        uint4 v3 = U[(size_t)s3 * QPN + q];
        float b0, b1;
        up2(v0.x, b0, b1); a0 += b0; a1 += b1;
        up2(v0.y, b0, b1); a2 += b0; a3 += b1;
        up2(v0.z, b0, b1); a4 += b0; a5 += b1;
        up2(v0.w, b0, b1); a6 += b0; a7 += b1;
        up2(v1.x, b0, b1); a0 += b0; a1 += b1;
        up2(v1.y, b0, b1); a2 += b0; a3 += b1;
        up2(v1.z, b0, b1); a4 += b0; a5 += b1;
        up2(v1.w, b0, b1); a6 += b0; a7 += b1;
        up2(v2.x, b0, b1); a0 += b0; a1 += b1;
        up2(v2.y, b0, b1); a2 += b0; a3 += b1;
        up2(v2.z, b0, b1); a4 += b0; a5 += b1;
        up2(v2.w, b0, b1); a6 += b0; a7 += b1;
        up2(v3.x, b0, b1); a0 += b0; a1 += b1;
        up2(v3.y, b0, b1); a2 += b0; a3 += b1;
        up2(v3.z, b0, b1); a4 += b0; a5 += b1;
        up2(v3.w, b0, b1); a6 += b0; a7 += b1;
    }
    for (; i < end; ++i) {
        uint4 v = U[(size_t)srcs[i] * QPN + q];
        float b0, b1;
        up2(v.x, b0, b1); a0 += b0; a1 += b1;
        up2(v.y, b0, b1); a2 += b0; a3 += b1;
        up2(v.z, b0, b1); a4 += b0; a5 += b1;
        up2(v.w, b0, b1); a6 += b0; a7 += b1;
    }

    float ds = dinv2[node];
    uint4 o;
    o.x = pk2(ds * a0, ds * a1);
    o.y = pk2(ds * a2, ds * a3);
    o.z = pk2(ds * a4, ds * a5);
    o.w = pk2(ds * a6, ds * a7);
    ((uint4*)unew)[(size_t)node * QPN + q] = o;
}

// ---------------- fused hop 3 + bias + log_softmax -> fp32 d_out ----------------
// y3 = D^{1/2} * dinv2 * (A u2 + u2) = dinv * (A u2 + u2).
// 51 nodes per 256-thread block (255 active); 5-lane groups never straddle blocks.
// Cross-lane max/sum via LDS.
__global__ __launch_bounds__(256) void propagate_lsm_kernel(const int* __restrict__ rowptr,
                                                            const int* __restrict__ srcs,
                                                            const float* __restrict__ dinv,
                                                            const unsigned* __restrict__ ucur,
                                                            const float* __restrict__ bias,
                                                            float* __restrict__ out, int n) {
    __shared__ float red[256];
    int tid = threadIdx.x;
    int gl = tid / QPN;                    // local group 0..50 (tid 255 -> 51, inactive)
    int q  = tid - gl * QPN;
    int node = blockIdx.x * NPB + gl;
    bool active = (gl < NPB) && (node < n);

    float a0 = 0, a1 = 0, a2 = 0, a3 = 0, a4 = 0, a5 = 0, a6 = 0, a7 = 0;
    float dv = 0.0f;
    if (active) {
        int beg = rowptr[node];
        int end = rowptr[node + 1];
        const uint4* U = (const uint4*)ucur;
        uint4 sv = U[(size_t)node * QPN + q];
        up2(sv.x, a0, a1); up2(sv.y, a2, a3); up2(sv.z, a4, a5); up2(sv.w, a6, a7);
        int i = beg;
        for (; i + 3 < end; i += 4) {
            int s0 = srcs[i], s1 = srcs[i + 1], s2 = srcs[i + 2], s3 = srcs[i + 3];
            uint4 v0 = U[(size_t)s0 * QPN + q];
            uint4 v1 = U[(size_t)s1 * QPN + q];
            uint4 v2 = U[(size_t)s2 * QPN + q];
            uint4 v3 = U[(size_t)s3 * QPN + q];
            float b0, b1;
            up2(v0.x, b0, b1); a0 += b0; a1 += b1;
            up2(v0.y, b0, b1); a2 += b0; a3 += b1;
            up2(v0.z, b0, b1); a4 += b0; a5 += b1;
            up2(v0.w, b0, b1); a6 += b0; a7 += b1;
            up2(v1.x, b0, b1); a0 += b0; a1 += b1;
            up2(v1.y, b0, b1); a2 += b0; a3 += b1;
            up2(v1.z, b0, b1); a4 += b0; a5 += b1;
            up2(v1.w, b0, b1); a6 += b0; a7 += b1;
            up2(v2.x, b0, b1); a0 += b0; a1 += b1;
            up2(v2.y, b0, b1); a2 += b0; a3 += b1;
            up2(v2.z, b0, b1); a4 += b0; a5 += b1;
            up2(v2.w, b0, b1); a6 += b0; a7 += b1;
            up2(v3.x, b0, b1); a0 += b0; a1 += b1;
            up2(v3.y, b0, b1); a2 += b0; a3 += b1;
            up2(v3.z, b0, b1); a4 += b0; a5 += b1;
            up2(v3.w, b0, b1); a6 += b0; a7 += b1;
        }
        for (; i < end; ++i) {
            uint4 v = U[(size_t)srcs[i] * QPN + q];
            float b0, b1;
            up2(v.x, b0, b1); a0 += b0; a1 += b1;
            up2(v.y, b0, b1); a2 += b0; a3 += b1;
            up2(v.z, b0, b1); a4 += b0; a5 += b1;
            up2(v.w, b0, b1); a6 += b0; a7 += b1;
        }
        dv = dinv[node];
    }

    // y_j = dv*a_j + bias[q*8+j]
    float y0 = dv * a0 + bias[q * 8 + 0];
    float y1 = dv * a1 + bias[q * 8 + 1];
    float y2 = dv * a2 + bias[q * 8 + 2];
    float y3 = dv * a3 + bias[q * 8 + 3];
    float y4 = dv * a4 + bias[q * 8 + 4];
    float y5 = dv * a5 + bias[q * 8 + 5];
    float y6 = dv * a6 + bias[q * 8 + 6];
    float y7 = dv * a7 + bias[q * 8 + 7];

    float pm = fmaxf(fmaxf(fmaxf(y0, y1), fmaxf(y2, y3)),
                     fmaxf(fmaxf(y4, y5), fmaxf(y6, y7)));
    red[tid] = active ? pm : -1e30f;
    __syncthreads();
    int base = tid - q;
    float mx = fmaxf(fmaxf(fmaxf(red[base], red[base + 1]), fmaxf(red[base + 2], red[base + 3])),
                     red[base + 4]);
    __syncthreads();
    float ps = __expf(y0 - mx) + __expf(y1 - mx) + __expf(y2 - mx) + __expf(y3 - mx)
             + __expf(y4 - mx) + __expf(y5 - mx) + __expf(y6 - mx) + __expf(y7 - mx);
    red[tid] = active ? ps : 0.0f;
    __syncthreads();
    float se = red[base] + red[base + 1] + red[base + 2] + red[base + 3] + red[base + 4];
    float lse = mx + __logf(se);

    if (active) {
        float4* p = (float4*)(out + (size_t)node * F_OUT + q * 8);
        float4 o0, o1;
        o0.x = y0 - lse; o0.y = y1 - lse; o0.z = y2 - lse; o0.w = y3 - lse;
        o1.x = y4 - lse; o1.y = y5 - lse; o1.z = y6 - lse; o1.w = y7 - lse;
        p[0] = o0;
        p[1] = o1;
    }
}

extern "C" void kernel_launch(void* const* d_in, const int* in_sizes, int n_in,
                              void* d_out, int out_size, void* d_ws, size_t ws_size,
                              hipStream_t stream) {
    const float* x  = (const float*)d_in[0];
    const int*   ei = (const int*)d_in[1];
    const float* W  = (const float*)d_in[2];
    const float* b  = (const float*)d_in[3];

    const int N = in_sizes[0] / F_IN;        // 100000
    const int E = in_sizes[1] / 2;           // 1280000
    const int* src = ei;
    const int* dst = ei + E;
    const int nbk = (N + (1 << BSHIFT) - 1) >> BSHIFT;   // 391

    // ---- workspace layout ----
    char* base = (char*)d_ws;
    size_t off = 0;
    auto alloc = [&](size_t bytes) {
        char* p = base + off;
        off = (off + bytes + 255) & ~(size_t)255;
        return p;
    };
    float*    dinv    = (float*)   alloc((size_t)N * 4);
    float*    dinv2   = (float*)   alloc((size_t)N * 4);
    int*      rowptr  = (int*)     alloc((size_t)(N + 1) * 4);
    int*      bfill   = (int*)     alloc((size_t)MAXB * 4);
    int*      ebase   = (int*)     alloc((size_t)MAXB * 4);
    unsigned* staging = (unsigned*)alloc((size_t)nbk * BCAP * 4);    // 6.4 MB
    int*      srcs_s  = (int*)     alloc((size_t)E * 4);
    unsigned* uA      = (unsigned*)alloc((size_t)N * USTRIDE * 4);   // 8 MB
    unsigned* uB      = (unsigned*)alloc((size_t)N * USTRIDE * 4);   // 8 MB
    float*    outp    = (float*)d_out;

    // 1) partition edges into dst-buckets (bfill = counts, memset-initialized)
    hipMemsetAsync(bfill, 0, (size_t)nbk * 4, stream);
    partition_kernel<<<(E + PART_TILE - 1) / PART_TILE, PART_BLK, 0, stream>>>(
        src, dst, bfill, staging, E, nbk);

    // 2) bucket-total scan + per-bucket finalize (rowptr/dinv + CSR scatter)
    btotal_scan_kernel<<<1, 512, 0, stream>>>(bfill, ebase, rowptr + N, nbk, E);
    bucket_finalize_kernel<<<nbk, 256, 0, stream>>>(staging, bfill, ebase, rowptr,
                                                    dinv, dinv2, srcs_s, N);

    // 3) projection u0 = dinv * (x @ W^T) -> bf16 uA  (2 nodes/thread)
    proj_kernel<<<((size_t)N * 2 + 255) / 256, 256, 0, stream>>>(x, W, dinv, uA, N);

    // 4) hops 1,2 in bf16 u-space: uA -> uB -> uA
    const int pt = N * QPN;                  // 500k threads
    const int pg = (pt + 255) / 256;
    propagate_kernel<<<pg, 256, 0, stream>>>(rowptr, srcs_s, dinv2, uA, uB, N);
    propagate_kernel<<<pg, 256, 0, stream>>>(rowptr, srcs_s, dinv2, uB, uA, N);

    // 5) fused hop 3 + bias + log_softmax -> d_out (fp32)
    const int fb = (N + NPB - 1) / NPB;      // 1962 blocks
    propagate_lsm_kernel<<<fb, 256, 0, stream>>>(rowptr, srcs_s, dinv, uA, b, outp, N);
}